// Round 8
// baseline (260.083 us; speedup 1.0000x reference)
//
#include <hip/hip_runtime.h>

#define B_ROWS 8192
#define D_IN   1024
#define NOUT   1024
#define NB     8
#define KTOT   (D_IN * (NB + 1))   // 9216
#define GM     256
#define GN     128
#define GK     64

typedef __attribute__((ext_vector_type(4))) float f32x4;
typedef __attribute__((ext_vector_type(8))) short bf16x8;

__device__ __forceinline__ unsigned short f2bf(float f) {
  union { float f; unsigned u; } v; v.f = f;
  unsigned r = v.u + 0x7fffu + ((v.u >> 16) & 1u);   // RNE
  return (unsigned short)(r >> 16);
}

__device__ __forceinline__ void load_lds16(const void* g, void* l) {
  __builtin_amdgcn_global_load_lds(
      (const __attribute__((address_space(1))) unsigned int*)g,
      (__attribute__((address_space(3))) unsigned int*)l, 16, 0, 0);
}

__device__ __forceinline__ void barrier_raw() {
  asm volatile("" ::: "memory");
  __builtin_amdgcn_s_barrier();
  asm volatile("" ::: "memory");
}

// ---------------- weights -> bf16, concatenated [NOUT][KTOT] ----------------
__global__ __launch_bounds__(256) void wconv_kernel(
    const float* __restrict__ bw, const float* __restrict__ sw,
    unsigned short* __restrict__ Wc) {
  const size_t idx = ((size_t)blockIdx.x * 256 + threadIdx.x) * 4;
  const int n = (int)(idx / KTOT);
  const int k = (int)(idx % KTOT);
  float4 f;
  if (k < D_IN)
    f = *reinterpret_cast<const float4*>(bw + (size_t)n * D_IN + k);
  else
    f = *reinterpret_cast<const float4*>(sw + (size_t)n * (D_IN * NB) + (k - D_IN));
  union { unsigned short us[4]; uint2 u2; } o;
  o.us[0] = f2bf(f.x); o.us[1] = f2bf(f.y); o.us[2] = f2bf(f.z); o.us[3] = f2bf(f.w);
  *reinterpret_cast<uint2*>(Wc + idx) = o.u2;
}

// ------------- LayerNorm + silu + (spline + rbf) feature matrix -------------
__global__ __launch_bounds__(256) void feat_kernel(
    const float* __restrict__ x, const float* __restrict__ lnw,
    const float* __restrict__ lnb, unsigned short* __restrict__ F, int row0) {
  const int row = row0 + blockIdx.x;
  const float* xr = x + (size_t)row * D_IN;
  const int t = threadIdx.x;
  float v[4];
  float s = 0.f, s2 = 0.f;
#pragma unroll
  for (int i = 0; i < 4; ++i) {
    v[i] = xr[t + 256 * i];
    s += v[i];
    s2 += v[i] * v[i];
  }
#pragma unroll
  for (int off = 32; off > 0; off >>= 1) {
    s += __shfl_xor(s, off);
    s2 += __shfl_xor(s2, off);
  }
  __shared__ float red[8];
  const int wid = t >> 6;
  if ((t & 63) == 0) { red[wid] = s; red[4 + wid] = s2; }
  __syncthreads();
  s  = red[0] + red[1] + red[2] + red[3];
  s2 = red[4] + red[5] + red[6] + red[7];
  const float mu = s * (1.f / D_IN);
  const float var = s2 * (1.f / D_IN) - mu * mu;
  const float rstd = rsqrtf(var + 1e-5f);
  unsigned short* Frow = F + (size_t)blockIdx.x * KTOT;
#pragma unroll
  for (int i = 0; i < 4; ++i) {
    const int d = t + 256 * i;
    const float xn = (v[i] - mu) * rstd * lnw[d] + lnb[d];
    Frow[d] = f2bf(xn / (1.f + __expf(-xn)));           // SiLU
    float b[11];
#pragma unroll
    for (int j = 0; j < 11; ++j) {
      const float gj = 0.6f * j - 3.3f;
      b[j] = (xn >= gj && xn < gj + 0.6f) ? 1.f : 0.f;
    }
#pragma unroll
    for (int k = 1; k <= 3; ++k) {
      const float inv = 1.f / (0.6f * k);
#pragma unroll
      for (int j = 0; j <= 10 - k; ++j) {
        const float gj = 0.6f * j - 3.3f;
        b[j] = (xn - gj) * inv * b[j] + (gj + 0.6f * (k + 1) - xn) * inv * b[j + 1];
      }
    }
    union { unsigned short us[8]; uint4 u4; } pk;
#pragma unroll
    for (int j = 0; j < 8; ++j) {
      const float c = -1.5f + (3.f / 7.f) * j;
      const float tt = (xn - c) * (7.f / 3.f);
      pk.us[j] = f2bf(b[j] + __expf(-tt * tt));
    }
    *reinterpret_cast<uint4*>(Frow + D_IN + (size_t)d * 8) = pk.u4;
  }
}

// ---- GEMM: C = F @ Wc^T, 256x128, ring-3, m201-style 2-phase-per-K-tile ----
// 8 waves 4Mx2N (64x64). Phase A: MFMA n{0,1}; phase B: MFMA n{2,3}.
// Every ds_read consumed exactly one phase after issue; 2 barriers/phase.
__global__ __launch_bounds__(512, 2) void gemm_kernel(
    const unsigned short* __restrict__ A, const unsigned short* __restrict__ Bw,
    float* __restrict__ C, int row0) {
  __shared__ unsigned short As[3][GM * GK];   // 3 x 32 KB
  __shared__ unsigned short Bs[3][GN * GK];   // 3 x 16 KB
  const int t = threadIdx.x;
  const int w = t >> 6, l = t & 63;
  const int wr = w >> 1, wc = w & 1;          // 4 x 2 waves, 64x64 each
  const int id = blockIdx.x;
  const int nbm = gridDim.x >> 3;             // grid = nbm * 8
  int bm, bn;
  if ((nbm & 7) == 0) {
    const int c = id & 7, j = id >> 3, q = nbm >> 3;
    bm = c + 8 * (j % q);                     // bm%8 == XCD id -> A-panel sharers co-XCD
    bn = j / q;
  } else {
    bm = id % nbm; bn = id / nbm;
  }
  const size_t Abase = (size_t)bm * GM * KTOT;
  const size_t Bbase = (size_t)bn * GN * KTOT;

  const int arow = l >> 3;             // row within an 8-row segment
  const int achk = (l & 7) ^ arow;     // pre-swizzled source chunk (T2 write side)

  f32x4 acc[4][4] = {};

  auto stageA = [&](int buf, int k0) {
#pragma unroll
    for (int i = 0; i < 4; ++i) {
      const int seg = w * 4 + i;                           // 8 rows per segment
      load_lds16(A + Abase + (size_t)(seg * 8 + arow) * KTOT + k0 + achk * 8,
                 (char*)&As[buf][0] + seg * 1024);
    }
  };
  auto stageB = [&](int buf, int k0) {
#pragma unroll
    for (int i = 0; i < 2; ++i) {
      const int seg = w * 2 + i;
      load_lds16(Bw + Bbase + (size_t)(seg * 8 + arow) * KTOT + k0 + achk * 8,
                 (char*)&Bs[buf][0] + seg * 1024);
    }
  };

  const int hi = l >> 4;
  const int rA = wr * 64 + (l & 15);
  const int rB = wc * 64 + (l & 15);
  const int rs = l & 7;
  const int cbk0 = (hi ^ rs) * 16;            // swizzled chunk byte offs, kk=0
  const int cbk1 = ((4 + hi) ^ rs) * 16;      // kk=1

  auto dsreadA = [&](int buf, bf16x8* a) {    // 8 reads: kk0 m0..3, kk1 m0..3
    const char* Asb = (const char*)&As[buf][0];
#pragma unroll
    for (int m = 0; m < 4; ++m)
      a[m] = *reinterpret_cast<const bf16x8*>(Asb + (rA + m * 16) * 128 + cbk0);
#pragma unroll
    for (int m = 0; m < 4; ++m)
      a[4 + m] = *reinterpret_cast<const bf16x8*>(Asb + (rA + m * 16) * 128 + cbk1);
  };
  auto dsreadB = [&](int buf, int nh, bf16x8* b) {  // 4 reads: n{2nh,2nh+1} x kk
    const char* Bsb = (const char*)&Bs[buf][0];
#pragma unroll
    for (int n = 0; n < 2; ++n)
      b[n] = *reinterpret_cast<const bf16x8*>(Bsb + (rB + (nh * 2 + n) * 16) * 128 + cbk0);
#pragma unroll
    for (int n = 0; n < 2; ++n)
      b[2 + n] = *reinterpret_cast<const bf16x8*>(Bsb + (rB + (nh * 2 + n) * 16) * 128 + cbk1);
  };
  auto mfma_half = [&](bf16x8* a, bf16x8* b, int nh) {
    __builtin_amdgcn_s_setprio(1);
#pragma unroll
    for (int kk = 0; kk < 2; ++kk)
#pragma unroll
      for (int m = 0; m < 4; ++m)
#pragma unroll
        for (int n = 0; n < 2; ++n)
          acc[m][nh * 2 + n] = __builtin_amdgcn_mfma_f32_16x16x32_bf16(
              a[kk * 4 + m], b[kk * 2 + n], acc[m][nh * 2 + n], 0, 0, 0);
    __builtin_amdgcn_s_setprio(0);
  };

  const int NT = KTOT / GK;            // 144
  // prologue: tiles 0,1 staged; tile 0 landed+published; tile0 A/B0 frags read
  stageA(0, 0);       stageB(0, 0);
  stageA(1, GK);      stageB(1, GK);
  asm volatile("s_waitcnt vmcnt(6)" ::: "memory");
  barrier_raw();
  bf16x8 aF[8], bF0[4], bF1[4];
  dsreadA(0, aF);
  dsreadB(0, 0, bF0);

  int cur = 0;
  for (int tt = 0; tt < NT; ++tt) {
    int nxt = cur + 1; if (nxt >= 3) nxt -= 3;
    int pre = cur + 2; if (pre >= 3) pre -= 3;
    // ======== phase A: MFMA(n0,n1) ; reads bF1(cur) ; stageA(t+2) ========
    dsreadB(cur, 1, bF1);
    if (tt + 2 < NT) {
      stageA(pre, (tt + 2) * GK);
      asm volatile("s_waitcnt vmcnt(4)" ::: "memory");   // tile t+1 landed; t+2 A in flight
    } else if (tt + 1 < NT) {
      asm volatile("s_waitcnt vmcnt(0)" ::: "memory");
    }
    barrier_raw();                      // publish tile t+1
    __builtin_amdgcn_sched_barrier(0);
    mfma_half(aF, bF0, 0);
    __builtin_amdgcn_sched_barrier(0);
    barrier_raw();                      // phase lock (protects slot reuse)
    // ======== phase B: MFMA(n2,n3) ; reads aF/bF0 of t+1 ; stageB(t+2) ====
    bf16x8 aN[8], bN[4];
    if (tt + 1 < NT) { dsreadA(nxt, aN); dsreadB(nxt, 0, bN); }
    if (tt + 2 < NT) stageB(pre, (tt + 2) * GK);
    barrier_raw();
    __builtin_amdgcn_sched_barrier(0);
    mfma_half(aF, bF1, 1);
    __builtin_amdgcn_sched_barrier(0);
    barrier_raw();
    if (tt + 1 < NT) {
#pragma unroll
      for (int i = 0; i < 8; ++i) aF[i] = aN[i];
#pragma unroll
      for (int i = 0; i < 4; ++i) bF0[i] = bN[i];
    }
    cur = nxt;
  }

  const int crow0 = row0 + bm * GM + wr * 64 + hi * 4;
  const int ccol0 = bn * GN + wc * 64 + (l & 15);
#pragma unroll
  for (int m = 0; m < 4; ++m)
#pragma unroll
    for (int n = 0; n < 4; ++n) {
      float* cp = C + (size_t)(crow0 + m * 16) * NOUT + ccol0 + n * 16;
#pragma unroll
      for (int r = 0; r < 4; ++r)
        cp[(size_t)r * NOUT] = acc[m][n][r];
    }
}

extern "C" void kernel_launch(void* const* d_in, const int* in_sizes, int n_in,
                              void* d_out, int out_size, void* d_ws, size_t ws_size,
                              hipStream_t stream) {
  const float* x   = (const float*)d_in[0];
  const float* lnw = (const float*)d_in[1];
  const float* lnb = (const float*)d_in[2];
  const float* bw  = (const float*)d_in[3];
  const float* sw  = (const float*)d_in[4];
  float* out = (float*)d_out;
  char* ws = (char*)d_ws;

  const size_t wc_bytes = (size_t)NOUT * KTOT * 2;   // ~18.9 MB
  unsigned short* Wc = (unsigned short*)ws;
  unsigned short* F  = (unsigned short*)(ws + wc_bytes);

  size_t avail = (ws_size > wc_bytes) ? ws_size - wc_bytes : 0;
  long long cm = (long long)(avail / ((size_t)KTOT * 2));
  cm &= ~255LL;
  if (cm < 256) cm = 256;
  if (cm > B_ROWS) cm = B_ROWS;
  const int chunkM = (int)cm;

  wconv_kernel<<<(NOUT * (KTOT / 4)) / 256, 256, 0, stream>>>(bw, sw, Wc);
  for (int r0 = 0; r0 < B_ROWS; r0 += chunkM) {
    int rows = B_ROWS - r0; if (rows > chunkM) rows = chunkM;
    feat_kernel<<<rows, 256, 0, stream>>>(x, lnw, lnb, F, r0);
    gemm_kernel<<<dim3((rows / GM) * (NOUT / GN)), 512, 0, stream>>>(F, Wc, out, r0);
  }
}

// Round 10
// 162.163 us; speedup vs baseline: 1.6038x; 1.6038x over previous
//
#include <hip/hip_runtime.h>

#define B_ROWS 8192
#define D_IN   1024
#define NOUT   1024
#define KB     1024          // base-branch K (bf16)
#define KS     8192          // spline-branch K (i8)
#define GM     256
#define GN     128
#define GK     64            // bf16 K-tile
#define GKS    128           // i8 K-tile (bytes == elements)

typedef __attribute__((ext_vector_type(4))) float f32x4;
typedef __attribute__((ext_vector_type(4))) int   i32x4;
typedef __attribute__((ext_vector_type(8))) short bf16x8;

#define SCALE_F 63.5f
#define SCALE_W 11494.728f   // 127 * sqrt(8192)

__device__ __forceinline__ unsigned short f2bf(float f) {
  union { float f; unsigned u; } v; v.f = f;
  unsigned r = v.u + 0x7fffu + ((v.u >> 16) & 1u);   // RNE
  return (unsigned short)(r >> 16);
}

__device__ __forceinline__ unsigned pk4(float a, float b, float c, float d, float s) {
  int qa = (int)rintf(fminf(fmaxf(a * s, -127.f), 127.f));
  int qb = (int)rintf(fminf(fmaxf(b * s, -127.f), 127.f));
  int qc = (int)rintf(fminf(fmaxf(c * s, -127.f), 127.f));
  int qd = (int)rintf(fminf(fmaxf(d * s, -127.f), 127.f));
  return (unsigned)(qa & 255) | ((unsigned)(qb & 255) << 8) |
         ((unsigned)(qc & 255) << 16) | ((unsigned)(qd & 255) << 24);
}

__device__ __forceinline__ void load_lds16(const void* g, void* l) {
  __builtin_amdgcn_global_load_lds(
      (const __attribute__((address_space(1))) unsigned int*)g,
      (__attribute__((address_space(3))) unsigned int*)l, 16, 0, 0);
}

__device__ __forceinline__ void barrier_raw() {
  asm volatile("" ::: "memory");
  __builtin_amdgcn_s_barrier();
  asm volatile("" ::: "memory");
}

// ---------------- base weights -> bf16 [NOUT][KB] ----------------
__global__ __launch_bounds__(256) void wconv_b(
    const float* __restrict__ bw, unsigned short* __restrict__ Wb) {
  const size_t idx = ((size_t)blockIdx.x * 256 + threadIdx.x) * 4;
  float4 f = *reinterpret_cast<const float4*>(bw + idx);
  union { unsigned short us[4]; uint2 u2; } o;
  o.us[0] = f2bf(f.x); o.us[1] = f2bf(f.y); o.us[2] = f2bf(f.z); o.us[3] = f2bf(f.w);
  *reinterpret_cast<uint2*>(Wb + idx) = o.u2;
}

// ------------- spline weights -> i8 x SCALE_W, linear [NOUT][KS] ------------
__global__ __launch_bounds__(256) void wconv_s(
    const float* __restrict__ sw, unsigned char* __restrict__ Ws) {
  const size_t base = ((size_t)blockIdx.x * 256 + threadIdx.x) * 8;
  float4 v0 = *reinterpret_cast<const float4*>(sw + base);
  float4 v1 = *reinterpret_cast<const float4*>(sw + base + 4);
  *reinterpret_cast<uint2*>(Ws + base) =
      make_uint2(pk4(v0.x, v0.y, v0.z, v0.w, SCALE_W),
                 pk4(v1.x, v1.y, v1.z, v1.w, SCALE_W));
}

// ------------- LayerNorm + silu(bf16) + (spline+rbf -> i8 linear) -----------
__global__ __launch_bounds__(256) void feat_kernel(
    const float* __restrict__ x, const float* __restrict__ lnw,
    const float* __restrict__ lnb, unsigned short* __restrict__ Fb,
    unsigned char* __restrict__ Fs, int row0) {
  const int row = row0 + blockIdx.x;
  const float* xr = x + (size_t)row * D_IN;
  const int t = threadIdx.x;
  float v[4];
  float s = 0.f, s2 = 0.f;
#pragma unroll
  for (int i = 0; i < 4; ++i) {
    v[i] = xr[t + 256 * i];
    s += v[i];
    s2 += v[i] * v[i];
  }
#pragma unroll
  for (int off = 32; off > 0; off >>= 1) {
    s += __shfl_xor(s, off);
    s2 += __shfl_xor(s2, off);
  }
  __shared__ float red[8];
  const int wid = t >> 6;
  if ((t & 63) == 0) { red[wid] = s; red[4 + wid] = s2; }
  __syncthreads();
  s  = red[0] + red[1] + red[2] + red[3];
  s2 = red[4] + red[5] + red[6] + red[7];
  const float mu = s * (1.f / D_IN);
  const float var = s2 * (1.f / D_IN) - mu * mu;
  const float rstd = rsqrtf(var + 1e-5f);
  unsigned short* fbr = Fb + (size_t)blockIdx.x * KB;
  unsigned char*  fsr = Fs + (size_t)blockIdx.x * KS;
#pragma unroll
  for (int i = 0; i < 4; ++i) {
    const int d = t + 256 * i;
    const float xn = (v[i] - mu) * rstd * lnw[d] + lnb[d];
    fbr[d] = f2bf(xn / (1.f + __expf(-xn)));            // SiLU
    float b[11];
#pragma unroll
    for (int j = 0; j < 11; ++j) {
      const float gj = 0.6f * j - 3.3f;
      b[j] = (xn >= gj && xn < gj + 0.6f) ? 1.f : 0.f;
    }
#pragma unroll
    for (int k = 1; k <= 3; ++k) {
      const float inv = 1.f / (0.6f * k);
#pragma unroll
      for (int j = 0; j <= 10 - k; ++j) {
        const float gj = 0.6f * j - 3.3f;
        b[j] = (xn - gj) * inv * b[j] + (gj + 0.6f * (k + 1) - xn) * inv * b[j + 1];
      }
    }
    float f[8];
#pragma unroll
    for (int j = 0; j < 8; ++j) {
      const float c = -1.5f + (3.f / 7.f) * j;
      const float tt = (xn - c) * (7.f / 3.f);
      f[j] = b[j] + __expf(-tt * tt);
    }
    *reinterpret_cast<uint2*>(fsr + d * 8) =
        make_uint2(pk4(f[0], f[1], f[2], f[3], SCALE_F),
                   pk4(f[4], f[5], f[6], f[7], SCALE_F));
  }
}

// ---- base GEMM (bf16, K=1024): C = Fb @ Wb^T. R5 structure, 256x128 tile ---
__global__ __launch_bounds__(512, 2) void gemm_base(
    const unsigned short* __restrict__ A, const unsigned short* __restrict__ Bw,
    float* __restrict__ C, int row0) {
  __shared__ unsigned short As[3][GM * GK];
  __shared__ unsigned short Bs[3][GN * GK];
  const int t = threadIdx.x;
  const int w = t >> 6, l = t & 63;
  const int wr = w >> 1, wc = w & 1;
  const int id = blockIdx.x;
  const int nbm = gridDim.x >> 3;
  int bm, bn;
  if ((nbm & 7) == 0) {
    const int c = id & 7, j = id >> 3, q = nbm >> 3;
    bm = c + 8 * (j % q);
    bn = j / q;
  } else { bm = id % nbm; bn = id / nbm; }
  const size_t Abase = (size_t)bm * GM * KB;
  const size_t Bbase = (size_t)bn * GN * KB;
  const int arow = l >> 3;
  const int achk = (l & 7) ^ arow;
  f32x4 acc[4][4] = {};
  auto stageA = [&](int buf, int k0) {
#pragma unroll
    for (int i = 0; i < 4; ++i) {
      const int seg = w * 4 + i;
      load_lds16(A + Abase + (size_t)(seg * 8 + arow) * KB + k0 + achk * 8,
                 (char*)&As[buf][0] + seg * 1024);
    }
  };
  auto stageB = [&](int buf, int k0) {
#pragma unroll
    for (int i = 0; i < 2; ++i) {
      const int seg = w * 2 + i;
      load_lds16(Bw + Bbase + (size_t)(seg * 8 + arow) * KB + k0 + achk * 8,
                 (char*)&Bs[buf][0] + seg * 1024);
    }
  };
  const int hi = l >> 4;
  const int rA = wr * 64 + (l & 15);
  const int rB = wc * 64 + (l & 15);
  const int rs = l & 7;
  auto dsread = [&](int buf, int kk, bf16x8* a, bf16x8* b) {
    const int cb = ((kk * 4 + hi) ^ rs) * 16;
#pragma unroll
    for (int m = 0; m < 4; ++m)
      a[m] = *reinterpret_cast<const bf16x8*>(
          (const char*)&As[buf][0] + (rA + m * 16) * 128 + cb);
#pragma unroll
    for (int n = 0; n < 4; ++n)
      b[n] = *reinterpret_cast<const bf16x8*>(
          (const char*)&Bs[buf][0] + (rB + n * 16) * 128 + cb);
  };
  auto domfma = [&](bf16x8* a, bf16x8* b) {
    __builtin_amdgcn_s_setprio(1);
#pragma unroll
    for (int m = 0; m < 4; ++m)
#pragma unroll
      for (int n = 0; n < 4; ++n)
        acc[m][n] = __builtin_amdgcn_mfma_f32_16x16x32_bf16(a[m], b[n], acc[m][n], 0, 0, 0);
    __builtin_amdgcn_s_setprio(0);
  };
  const int NT = KB / GK;              // 16
  stageA(0, 0); stageB(0, 0);
  stageA(1, GK); stageB(1, GK);
  asm volatile("s_waitcnt vmcnt(6)" ::: "memory");
  barrier_raw();
  int cur = 0;
  for (int tt = 0; tt < NT; ++tt) {
    int pre = cur + 2; if (pre >= 3) pre -= 3;
    const bool have2 = (tt + 2 < NT);
    bf16x8 a0[4], b0[4], a1[4], b1[4];
    dsread(cur, 0, a0, b0);
    dsread(cur, 1, a1, b1);
    if (have2) { stageA(pre, (tt + 2) * GK); stageB(pre, (tt + 2) * GK); }
    __builtin_amdgcn_sched_barrier(0);
    domfma(a0, b0);
    __builtin_amdgcn_sched_barrier(0);
    domfma(a1, b1);
    if (tt + 1 < NT) {
      if (have2) asm volatile("s_waitcnt vmcnt(6)" ::: "memory");
      else       asm volatile("s_waitcnt vmcnt(0)" ::: "memory");
      barrier_raw();
    }
    cur = cur + 1; if (cur >= 3) cur = 0;
  }
  const int crow0 = row0 + bm * GM + wr * 64 + hi * 4;
  const int ccol0 = bn * GN + wc * 64 + (l & 15);
#pragma unroll
  for (int m = 0; m < 4; ++m)
#pragma unroll
    for (int n = 0; n < 4; ++n) {
      float* cp = C + (size_t)(crow0 + m * 16) * NOUT + ccol0 + n * 16;
#pragma unroll
      for (int r = 0; r < 4; ++r)
        cp[(size_t)r * NOUT] = acc[m][n][r];
    }
}

// ---- spline GEMM (i8, K=8192): C += acc/(SF*SW). 256x128, GKS=128, ring-3 --
// mfma_i32_16x16x64_i8: one b128 read = one full-K fragment (16 consecutive i8
// per lane per k-group, pattern verified via bf16/fp8). Same R5 schedule.
__global__ __launch_bounds__(512, 2) void gemm_spline(
    const unsigned char* __restrict__ Fs, const unsigned char* __restrict__ Ws,
    float* __restrict__ C, int row0) {
  __shared__ __align__(16) unsigned char As[3][GM * GKS];   // 3 x 32 KB
  __shared__ __align__(16) unsigned char Bs[3][GN * GKS];   // 3 x 16 KB
  const int t = threadIdx.x;
  const int w = t >> 6, l = t & 63;
  const int wr = w >> 1, wc = w & 1;          // 4x2 waves, 64x64 each
  const int id = blockIdx.x;
  const int nbm = gridDim.x >> 3;
  int bm, bn;
  if ((nbm & 7) == 0) {
    const int c = id & 7, j = id >> 3, q = nbm >> 3;
    bm = c + 8 * (j % q);                     // bm%8 == XCD id
    bn = j / q;
  } else { bm = id % nbm; bn = id / nbm; }
  const size_t Ab = (size_t)bm * GM * KS;
  const size_t Bb = (size_t)bn * GN * KS;
  i32x4 acc[4][4] = {};
  auto stageA = [&](int buf, int k0) {
#pragma unroll
    for (int i = 0; i < 4; ++i) {
      const int ch = i * 512 + t;             // 2048 chunks: row=ch>>3, c=ch&7
      const int r = ch >> 3, c = ch & 7;
      load_lds16(Fs + Ab + (size_t)r * KS + k0 + ((c ^ (r & 7)) * 16),
                 (char*)&As[buf][0] + ch * 16);
    }
  };
  auto stageB = [&](int buf, int k0) {
#pragma unroll
    for (int i = 0; i < 2; ++i) {
      const int ch = i * 512 + t;             // 1024 chunks
      const int r = ch >> 3, c = ch & 7;
      load_lds16(Ws + Bb + (size_t)r * KS + k0 + ((c ^ (r & 7)) * 16),
                 (char*)&Bs[buf][0] + ch * 16);
    }
  };
  const int hi = l >> 4, l15 = l & 15, rs = l & 7;
  const int c0 = (hi ^ rs) * 16;              // ks=0 swizzled chunk
  const int c1 = ((4 + hi) ^ rs) * 16;        // ks=1
  i32x4 a0[4], a1[4], b0[4], b1[4];
  auto dsread = [&](int buf) {
    const char* Asb = (const char*)&As[buf][0];
    const char* Bsb = (const char*)&Bs[buf][0];
#pragma unroll
    for (int m = 0; m < 4; ++m) {
      a0[m] = *reinterpret_cast<const i32x4*>(Asb + (wr * 64 + l15 + m * 16) * 128 + c0);
      a1[m] = *reinterpret_cast<const i32x4*>(Asb + (wr * 64 + l15 + m * 16) * 128 + c1);
    }
#pragma unroll
    for (int n = 0; n < 4; ++n) {
      b0[n] = *reinterpret_cast<const i32x4*>(Bsb + (wc * 64 + l15 + n * 16) * 128 + c0);
      b1[n] = *reinterpret_cast<const i32x4*>(Bsb + (wc * 64 + l15 + n * 16) * 128 + c1);
    }
  };
  auto domfma = [&]() {
    __builtin_amdgcn_s_setprio(1);
#pragma unroll
    for (int m = 0; m < 4; ++m)
#pragma unroll
      for (int n = 0; n < 4; ++n)
        acc[m][n] = __builtin_amdgcn_mfma_i32_16x16x64_i8(a0[m], b0[n], acc[m][n], 0, 0, 0);
#pragma unroll
    for (int m = 0; m < 4; ++m)
#pragma unroll
      for (int n = 0; n < 4; ++n)
        acc[m][n] = __builtin_amdgcn_mfma_i32_16x16x64_i8(a1[m], b1[n], acc[m][n], 0, 0, 0);
    __builtin_amdgcn_s_setprio(0);
  };
  const int NT = KS / GKS;             // 64
  stageA(0, 0); stageB(0, 0);
  stageA(1, GKS); stageB(1, GKS);
  asm volatile("s_waitcnt vmcnt(6)" ::: "memory");
  barrier_raw();
  int cur = 0;
  for (int tt = 0; tt < NT; ++tt) {
    int pre = cur + 2; if (pre >= 3) pre -= 3;
    const bool have2 = (tt + 2 < NT);
    dsread(cur);
    if (have2) { stageA(pre, (tt + 2) * GKS); stageB(pre, (tt + 2) * GKS); }
    __builtin_amdgcn_sched_barrier(0);
    domfma();
    if (tt + 1 < NT) {
      if (have2) asm volatile("s_waitcnt vmcnt(6)" ::: "memory");
      else       asm volatile("s_waitcnt vmcnt(0)" ::: "memory");
      barrier_raw();
    }
    cur = cur + 1; if (cur >= 3) cur = 0;
  }
  const float sc = 1.0f / (SCALE_F * SCALE_W);
  const int crow0 = row0 + bm * GM + wr * 64 + hi * 4;
  const int ccol0 = bn * GN + wc * 64 + l15;
#pragma unroll
  for (int m = 0; m < 4; ++m)
#pragma unroll
    for (int n = 0; n < 4; ++n) {
      float* cp = C + (size_t)(crow0 + m * 16) * NOUT + ccol0 + n * 16;
#pragma unroll
      for (int r = 0; r < 4; ++r)
        cp[(size_t)r * NOUT] += (float)acc[m][n][r] * sc;
    }
}

extern "C" void kernel_launch(void* const* d_in, const int* in_sizes, int n_in,
                              void* d_out, int out_size, void* d_ws, size_t ws_size,
                              hipStream_t stream) {
  const float* x   = (const float*)d_in[0];
  const float* lnw = (const float*)d_in[1];
  const float* lnb = (const float*)d_in[2];
  const float* bw  = (const float*)d_in[3];
  const float* sw  = (const float*)d_in[4];
  float* out = (float*)d_out;
  char* ws = (char*)d_ws;

  const size_t wb_bytes = (size_t)NOUT * KB * 2;    // 2 MB
  const size_t wsq_bytes = (size_t)NOUT * KS;       // 8 MB
  unsigned short* Wb = (unsigned short*)ws;
  unsigned char*  Wsp = (unsigned char*)(ws + wb_bytes);
  char* fbase = ws + wb_bytes + wsq_bytes;

  const size_t per_row = (size_t)KB * 2 + KS;       // 10240 B
  size_t avail = (ws_size > wb_bytes + wsq_bytes) ? ws_size - wb_bytes - wsq_bytes : 0;
  long long cm = (long long)(avail / per_row);
  cm &= ~255LL;
  if (cm < 256) cm = 256;
  if (cm > B_ROWS) cm = B_ROWS;
  const int chunkM = (int)cm;
  unsigned short* Fb = (unsigned short*)fbase;
  unsigned char*  Fs = (unsigned char*)(fbase + (size_t)chunkM * KB * 2);

  wconv_b<<<(NOUT * KB / 4) / 256, 256, 0, stream>>>(bw, Wb);
  wconv_s<<<(NOUT * KS / 8) / 256, 256, 0, stream>>>(sw, Wsp);
  for (int r0 = 0; r0 < B_ROWS; r0 += chunkM) {
    int rows = B_ROWS - r0; if (rows > chunkM) rows = chunkM;
    feat_kernel<<<rows, 256, 0, stream>>>(x, lnw, lnb, Fb, Fs, r0);
    gemm_base<<<dim3((rows / GM) * (NOUT / GN)), 512, 0, stream>>>(Fb, Wb, out, r0);
    gemm_spline<<<dim3((rows / GM) * (NOUT / GN)), 512, 0, stream>>>(Fs, Wsp, out, r0);
  }
}

// Round 11
// 122.251 us; speedup vs baseline: 2.1274x; 1.3265x over previous
//
#include <hip/hip_runtime.h>

#define B_ROWS 8192
#define D_IN   1024
#define NOUT   1024
#define KB     1024          // base-branch K (bf16)
#define KS     8192          // spline-branch K (i8)
#define GM     256
#define GN     128
#define GK     64            // bf16 K-tile
#define GKS    128           // i8 K-tile (bytes == elements)

#define TBL_N  2048
#define TBL_X0 (-5.5f)
#define TBL_W  11.0f

typedef __attribute__((ext_vector_type(4))) float f32x4;
typedef __attribute__((ext_vector_type(4))) int   i32x4;
typedef __attribute__((ext_vector_type(8))) short bf16x8;

#define SCALE_F 63.5f
#define SCALE_W 11494.728f   // 127 * sqrt(8192)

__device__ __forceinline__ unsigned short f2bf(float f) {
  union { float f; unsigned u; } v; v.f = f;
  unsigned r = v.u + 0x7fffu + ((v.u >> 16) & 1u);   // RNE
  return (unsigned short)(r >> 16);
}

__device__ __forceinline__ unsigned pk4(float a, float b, float c, float d, float s) {
  int qa = (int)rintf(fminf(fmaxf(a * s, -127.f), 127.f));
  int qb = (int)rintf(fminf(fmaxf(b * s, -127.f), 127.f));
  int qc = (int)rintf(fminf(fmaxf(c * s, -127.f), 127.f));
  int qd = (int)rintf(fminf(fmaxf(d * s, -127.f), 127.f));
  return (unsigned)(qa & 255) | ((unsigned)(qb & 255) << 8) |
         ((unsigned)(qc & 255) << 16) | ((unsigned)(qd & 255) << 24);
}

__device__ __forceinline__ void load_lds16(const void* g, void* l) {
  __builtin_amdgcn_global_load_lds(
      (const __attribute__((address_space(1))) unsigned int*)g,
      (__attribute__((address_space(3))) unsigned int*)l, 16, 0, 0);
}

__device__ __forceinline__ void barrier_raw() {
  asm volatile("" ::: "memory");
  __builtin_amdgcn_s_barrier();
  asm volatile("" ::: "memory");
}

// ---- spline+rbf feature table: T[k] = 8 x i8 of round(63.5*(b_j+rbf_j)) ----
__global__ __launch_bounds__(256) void tbl_kernel(unsigned char* __restrict__ T) {
  const int k = blockIdx.x * 256 + threadIdx.x;   // grid = TBL_N/256
  const float xn = TBL_X0 + (TBL_W / TBL_N) * k;
  float b[11];
#pragma unroll
  for (int j = 0; j < 11; ++j) {
    const float gj = 0.6f * j - 3.3f;
    b[j] = (xn >= gj && xn < gj + 0.6f) ? 1.f : 0.f;
  }
#pragma unroll
  for (int kk = 1; kk <= 3; ++kk) {
    const float inv = 1.f / (0.6f * kk);
#pragma unroll
    for (int j = 0; j <= 10 - kk; ++j) {
      const float gj = 0.6f * j - 3.3f;
      b[j] = (xn - gj) * inv * b[j] + (gj + 0.6f * (kk + 1) - xn) * inv * b[j + 1];
    }
  }
  float f[8];
#pragma unroll
  for (int j = 0; j < 8; ++j) {
    const float c = -1.5f + (3.f / 7.f) * j;
    const float tt = (xn - c) * (7.f / 3.f);
    f[j] = b[j] + __expf(-tt * tt);
  }
  *reinterpret_cast<uint2*>(T + (size_t)k * 8) =
      make_uint2(pk4(f[0], f[1], f[2], f[3], SCALE_F),
                 pk4(f[4], f[5], f[6], f[7], SCALE_F));
}

// ---------------- base weights -> bf16 [NOUT][KB] ----------------
__global__ __launch_bounds__(256) void wconv_b(
    const float* __restrict__ bw, unsigned short* __restrict__ Wb) {
  const size_t idx = ((size_t)blockIdx.x * 256 + threadIdx.x) * 4;
  float4 f = *reinterpret_cast<const float4*>(bw + idx);
  union { unsigned short us[4]; uint2 u2; } o;
  o.us[0] = f2bf(f.x); o.us[1] = f2bf(f.y); o.us[2] = f2bf(f.z); o.us[3] = f2bf(f.w);
  *reinterpret_cast<uint2*>(Wb + idx) = o.u2;
}

// ------------- spline weights -> i8 x SCALE_W, linear [NOUT][KS] ------------
__global__ __launch_bounds__(256) void wconv_s(
    const float* __restrict__ sw, unsigned char* __restrict__ Ws) {
  const size_t base = ((size_t)blockIdx.x * 256 + threadIdx.x) * 8;
  float4 v0 = *reinterpret_cast<const float4*>(sw + base);
  float4 v1 = *reinterpret_cast<const float4*>(sw + base + 4);
  *reinterpret_cast<uint2*>(Ws + base) =
      make_uint2(pk4(v0.x, v0.y, v0.z, v0.w, SCALE_W),
                 pk4(v1.x, v1.y, v1.z, v1.w, SCALE_W));
}

// -------- LayerNorm + silu(bf16) + table-lookup spline+rbf (i8) -------------
__global__ __launch_bounds__(256) void feat_kernel(
    const float* __restrict__ x, const float* __restrict__ lnw,
    const float* __restrict__ lnb, const unsigned char* __restrict__ T,
    unsigned short* __restrict__ Fb, unsigned char* __restrict__ Fs, int row0) {
  const int row = row0 + blockIdx.x;
  const float* xr = x + (size_t)row * D_IN;
  const int t = threadIdx.x;
  float v[4];
  float s = 0.f, s2 = 0.f;
#pragma unroll
  for (int i = 0; i < 4; ++i) {
    v[i] = xr[t + 256 * i];
    s += v[i];
    s2 += v[i] * v[i];
  }
#pragma unroll
  for (int off = 32; off > 0; off >>= 1) {
    s += __shfl_xor(s, off);
    s2 += __shfl_xor(s2, off);
  }
  __shared__ float red[8];
  const int wid = t >> 6;
  if ((t & 63) == 0) { red[wid] = s; red[4 + wid] = s2; }
  __syncthreads();
  s  = red[0] + red[1] + red[2] + red[3];
  s2 = red[4] + red[5] + red[6] + red[7];
  const float mu = s * (1.f / D_IN);
  const float var = s2 * (1.f / D_IN) - mu * mu;
  const float rstd = rsqrtf(var + 1e-5f);
  unsigned short* fbr = Fb + (size_t)blockIdx.x * KB;
  unsigned char*  fsr = Fs + (size_t)blockIdx.x * KS;
#pragma unroll
  for (int i = 0; i < 4; ++i) {
    const int d = t + 256 * i;
    const float xn = (v[i] - mu) * rstd * lnw[d] + lnb[d];
    const float e = __expf(-xn);
    fbr[d] = f2bf(xn * __builtin_amdgcn_rcpf(1.f + e));   // SiLU
    int ti = (int)rintf((xn - TBL_X0) * (TBL_N / TBL_W));
    ti = min(max(ti, 0), TBL_N - 1);
    *reinterpret_cast<uint2*>(fsr + d * 8) =
        *reinterpret_cast<const uint2*>(T + (size_t)ti * 8);
  }
}

// ---- base GEMM (bf16, K=1024): C = Fb @ Wb^T. R5 structure, 256x128 tile ---
__global__ __launch_bounds__(512, 2) void gemm_base(
    const unsigned short* __restrict__ A, const unsigned short* __restrict__ Bw,
    float* __restrict__ C, int row0) {
  __shared__ unsigned short As[3][GM * GK];
  __shared__ unsigned short Bs[3][GN * GK];
  const int t = threadIdx.x;
  const int w = t >> 6, l = t & 63;
  const int wr = w >> 1, wc = w & 1;
  const int id = blockIdx.x;
  const int nbm = gridDim.x >> 3;
  int bm, bn;
  if ((nbm & 7) == 0) {
    const int c = id & 7, j = id >> 3, q = nbm >> 3;
    bm = c + 8 * (j % q);
    bn = j / q;
  } else { bm = id % nbm; bn = id / nbm; }
  const size_t Abase = (size_t)bm * GM * KB;
  const size_t Bbase = (size_t)bn * GN * KB;
  const int arow = l >> 3;
  const int achk = (l & 7) ^ arow;
  f32x4 acc[4][4] = {};
  auto stageA = [&](int buf, int k0) {
#pragma unroll
    for (int i = 0; i < 4; ++i) {
      const int seg = w * 4 + i;
      load_lds16(A + Abase + (size_t)(seg * 8 + arow) * KB + k0 + achk * 8,
                 (char*)&As[buf][0] + seg * 1024);
    }
  };
  auto stageB = [&](int buf, int k0) {
#pragma unroll
    for (int i = 0; i < 2; ++i) {
      const int seg = w * 2 + i;
      load_lds16(Bw + Bbase + (size_t)(seg * 8 + arow) * KB + k0 + achk * 8,
                 (char*)&Bs[buf][0] + seg * 1024);
    }
  };
  const int hi = l >> 4;
  const int rA = wr * 64 + (l & 15);
  const int rB = wc * 64 + (l & 15);
  const int rs = l & 7;
  auto dsread = [&](int buf, int kk, bf16x8* a, bf16x8* b) {
    const int cb = ((kk * 4 + hi) ^ rs) * 16;
#pragma unroll
    for (int m = 0; m < 4; ++m)
      a[m] = *reinterpret_cast<const bf16x8*>(
          (const char*)&As[buf][0] + (rA + m * 16) * 128 + cb);
#pragma unroll
    for (int n = 0; n < 4; ++n)
      b[n] = *reinterpret_cast<const bf16x8*>(
          (const char*)&Bs[buf][0] + (rB + n * 16) * 128 + cb);
  };
  auto domfma = [&](bf16x8* a, bf16x8* b) {
    __builtin_amdgcn_s_setprio(1);
#pragma unroll
    for (int m = 0; m < 4; ++m)
#pragma unroll
      for (int n = 0; n < 4; ++n)
        acc[m][n] = __builtin_amdgcn_mfma_f32_16x16x32_bf16(a[m], b[n], acc[m][n], 0, 0, 0);
    __builtin_amdgcn_s_setprio(0);
  };
  const int NT = KB / GK;              // 16
  stageA(0, 0); stageB(0, 0);
  stageA(1, GK); stageB(1, GK);
  asm volatile("s_waitcnt vmcnt(6)" ::: "memory");
  barrier_raw();
  int cur = 0;
  for (int tt = 0; tt < NT; ++tt) {
    int pre = cur + 2; if (pre >= 3) pre -= 3;
    const bool have2 = (tt + 2 < NT);
    bf16x8 a0[4], b0[4], a1[4], b1[4];
    dsread(cur, 0, a0, b0);
    dsread(cur, 1, a1, b1);
    if (have2) { stageA(pre, (tt + 2) * GK); stageB(pre, (tt + 2) * GK); }
    __builtin_amdgcn_sched_barrier(0);
    domfma(a0, b0);
    __builtin_amdgcn_sched_barrier(0);
    domfma(a1, b1);
    if (tt + 1 < NT) {
      if (have2) asm volatile("s_waitcnt vmcnt(6)" ::: "memory");
      else       asm volatile("s_waitcnt vmcnt(0)" ::: "memory");
      barrier_raw();
    }
    cur = cur + 1; if (cur >= 3) cur = 0;
  }
  const int crow0 = row0 + bm * GM + wr * 64 + hi * 4;
  const int ccol0 = bn * GN + wc * 64 + (l & 15);
#pragma unroll
  for (int m = 0; m < 4; ++m)
#pragma unroll
    for (int n = 0; n < 4; ++n) {
      float* cp = C + (size_t)(crow0 + m * 16) * NOUT + ccol0 + n * 16;
#pragma unroll
      for (int r = 0; r < 4; ++r)
        cp[(size_t)r * NOUT] = acc[m][n][r];
    }
}

// ---- spline GEMM (i8, K=8192): C += acc/(SF*SW). 256x128, GKS=128, ring-3 --
__global__ __launch_bounds__(512, 2) void gemm_spline(
    const unsigned char* __restrict__ Fs, const unsigned char* __restrict__ Ws,
    float* __restrict__ C, int row0) {
  __shared__ __align__(16) unsigned char As[3][GM * GKS];   // 3 x 32 KB
  __shared__ __align__(16) unsigned char Bs[3][GN * GKS];   // 3 x 16 KB
  const int t = threadIdx.x;
  const int w = t >> 6, l = t & 63;
  const int wr = w >> 1, wc = w & 1;          // 4x2 waves, 64x64 each
  const int id = blockIdx.x;
  const int nbm = gridDim.x >> 3;
  int bm, bn;
  if ((nbm & 7) == 0) {
    const int c = id & 7, j = id >> 3, q = nbm >> 3;
    bm = c + 8 * (j % q);                     // bm%8 == XCD id
    bn = j / q;
  } else { bm = id % nbm; bn = id / nbm; }
  const size_t Ab = (size_t)bm * GM * KS;
  const size_t Bb = (size_t)bn * GN * KS;
  i32x4 acc[4][4] = {};
  auto stageA = [&](int buf, int k0) {
#pragma unroll
    for (int i = 0; i < 4; ++i) {
      const int ch = i * 512 + t;             // 2048 chunks: row=ch>>3, c=ch&7
      const int r = ch >> 3, c = ch & 7;
      load_lds16(Fs + Ab + (size_t)r * KS + k0 + ((c ^ (r & 7)) * 16),
                 (char*)&As[buf][0] + ch * 16);
    }
  };
  auto stageB = [&](int buf, int k0) {
#pragma unroll
    for (int i = 0; i < 2; ++i) {
      const int ch = i * 512 + t;             // 1024 chunks
      const int r = ch >> 3, c = ch & 7;
      load_lds16(Ws + Bb + (size_t)r * KS + k0 + ((c ^ (r & 7)) * 16),
                 (char*)&Bs[buf][0] + ch * 16);
    }
  };
  const int hi = l >> 4, l15 = l & 15, rs = l & 7;
  const int c0 = (hi ^ rs) * 16;              // ks=0 swizzled chunk
  const int c1 = ((4 + hi) ^ rs) * 16;        // ks=1
  i32x4 a0[4], a1[4], b0[4], b1[4];
  auto dsread = [&](int buf) {
    const char* Asb = (const char*)&As[buf][0];
    const char* Bsb = (const char*)&Bs[buf][0];
#pragma unroll
    for (int m = 0; m < 4; ++m) {
      a0[m] = *reinterpret_cast<const i32x4*>(Asb + (wr * 64 + l15 + m * 16) * 128 + c0);
      a1[m] = *reinterpret_cast<const i32x4*>(Asb + (wr * 64 + l15 + m * 16) * 128 + c1);
    }
#pragma unroll
    for (int n = 0; n < 4; ++n) {
      b0[n] = *reinterpret_cast<const i32x4*>(Bsb + (wc * 64 + l15 + n * 16) * 128 + c0);
      b1[n] = *reinterpret_cast<const i32x4*>(Bsb + (wc * 64 + l15 + n * 16) * 128 + c1);
    }
  };
  auto domfma = [&]() {
    __builtin_amdgcn_s_setprio(1);
#pragma unroll
    for (int m = 0; m < 4; ++m)
#pragma unroll
      for (int n = 0; n < 4; ++n)
        acc[m][n] = __builtin_amdgcn_mfma_i32_16x16x64_i8(a0[m], b0[n], acc[m][n], 0, 0, 0);
#pragma unroll
    for (int m = 0; m < 4; ++m)
#pragma unroll
      for (int n = 0; n < 4; ++n)
        acc[m][n] = __builtin_amdgcn_mfma_i32_16x16x64_i8(a1[m], b1[n], acc[m][n], 0, 0, 0);
    __builtin_amdgcn_s_setprio(0);
  };
  const int NT = KS / GKS;             // 64
  stageA(0, 0); stageB(0, 0);
  stageA(1, GKS); stageB(1, GKS);
  asm volatile("s_waitcnt vmcnt(6)" ::: "memory");
  barrier_raw();
  int cur = 0;
  for (int tt = 0; tt < NT; ++tt) {
    int pre = cur + 2; if (pre >= 3) pre -= 3;
    const bool have2 = (tt + 2 < NT);
    dsread(cur);
    if (have2) { stageA(pre, (tt + 2) * GKS); stageB(pre, (tt + 2) * GKS); }
    __builtin_amdgcn_sched_barrier(0);
    domfma();
    if (tt + 1 < NT) {
      if (have2) asm volatile("s_waitcnt vmcnt(6)" ::: "memory");
      else       asm volatile("s_waitcnt vmcnt(0)" ::: "memory");
      barrier_raw();
    }
    cur = cur + 1; if (cur >= 3) cur = 0;
  }
  const float sc = 1.0f / (SCALE_F * SCALE_W);
  const int crow0 = row0 + bm * GM + wr * 64 + hi * 4;
  const int ccol0 = bn * GN + wc * 64 + l15;
#pragma unroll
  for (int m = 0; m < 4; ++m)
#pragma unroll
    for (int n = 0; n < 4; ++n) {
      float* cp = C + (size_t)(crow0 + m * 16) * NOUT + ccol0 + n * 16;
#pragma unroll
      for (int r = 0; r < 4; ++r)
        cp[(size_t)r * NOUT] += (float)acc[m][n][r] * sc;
    }
}

extern "C" void kernel_launch(void* const* d_in, const int* in_sizes, int n_in,
                              void* d_out, int out_size, void* d_ws, size_t ws_size,
                              hipStream_t stream) {
  const float* x   = (const float*)d_in[0];
  const float* lnw = (const float*)d_in[1];
  const float* lnb = (const float*)d_in[2];
  const float* bw  = (const float*)d_in[3];
  const float* sw  = (const float*)d_in[4];
  float* out = (float*)d_out;
  char* ws = (char*)d_ws;

  const size_t tbl_bytes = (size_t)TBL_N * 8;       // 16 KB
  const size_t wb_bytes = (size_t)NOUT * KB * 2;    // 2 MB
  const size_t wsq_bytes = (size_t)NOUT * KS;       // 8 MB
  unsigned char*  T   = (unsigned char*)ws;
  unsigned short* Wb  = (unsigned short*)(ws + tbl_bytes);
  unsigned char*  Wsp = (unsigned char*)(ws + tbl_bytes + wb_bytes);
  char* fbase = ws + tbl_bytes + wb_bytes + wsq_bytes;

  const size_t hdr = tbl_bytes + wb_bytes + wsq_bytes;
  const size_t per_row = (size_t)KB * 2 + KS;       // 10240 B
  size_t avail = (ws_size > hdr) ? ws_size - hdr : 0;
  long long cm = (long long)(avail / per_row);
  cm &= ~255LL;
  if (cm < 256) cm = 256;
  if (cm > B_ROWS) cm = B_ROWS;
  const int chunkM = (int)cm;
  unsigned short* Fb = (unsigned short*)fbase;
  unsigned char*  Fs = (unsigned char*)(fbase + (size_t)chunkM * KB * 2);

  tbl_kernel<<<TBL_N / 256, 256, 0, stream>>>(T);
  wconv_b<<<(NOUT * KB / 4) / 256, 256, 0, stream>>>(bw, Wb);
  wconv_s<<<(NOUT * KS / 8) / 256, 256, 0, stream>>>(sw, Wsp);
  for (int r0 = 0; r0 < B_ROWS; r0 += chunkM) {
    int rows = B_ROWS - r0; if (rows > chunkM) rows = chunkM;
    feat_kernel<<<rows, 256, 0, stream>>>(x, lnw, lnb, T, Fb, Fs, r0);
    gemm_base<<<dim3((rows / GM) * (NOUT / GN)), 512, 0, stream>>>(Fb, Wb, out, r0);
    gemm_spline<<<dim3((rows / GM) * (NOUT / GN)), 512, 0, stream>>>(Fs, Wsp, out, r0);
  }
}

// Round 12
// 112.745 us; speedup vs baseline: 2.3068x; 1.0843x over previous
//
#include <hip/hip_runtime.h>

#define B_ROWS 8192
#define D_IN   1024
#define NOUT   1024
#define KB     1024          // base-branch K (bf16)
#define KS     8192          // spline-branch K (i8)
#define GM     256
#define GN     128
#define GK     64            // bf16 K-tile
#define GKS    128           // i8 K-tile (bytes == elements)

#define TBL_N  2048
#define TBL_X0 (-5.5f)
#define TBL_W  11.0f

typedef __attribute__((ext_vector_type(4))) float f32x4;
typedef __attribute__((ext_vector_type(4))) int   i32x4;
typedef __attribute__((ext_vector_type(8))) short bf16x8;

#define SCALE_F 63.5f
#define SCALE_W 11494.728f   // 127 * sqrt(8192)

__device__ __forceinline__ unsigned short f2bf(float f) {
  union { float f; unsigned u; } v; v.f = f;
  unsigned r = v.u + 0x7fffu + ((v.u >> 16) & 1u);   // RNE
  return (unsigned short)(r >> 16);
}

__device__ __forceinline__ unsigned pk4(float a, float b, float c, float d, float s) {
  int qa = (int)rintf(fminf(fmaxf(a * s, -127.f), 127.f));
  int qb = (int)rintf(fminf(fmaxf(b * s, -127.f), 127.f));
  int qc = (int)rintf(fminf(fmaxf(c * s, -127.f), 127.f));
  int qd = (int)rintf(fminf(fmaxf(d * s, -127.f), 127.f));
  return (unsigned)(qa & 255) | ((unsigned)(qb & 255) << 8) |
         ((unsigned)(qc & 255) << 16) | ((unsigned)(qd & 255) << 24);
}

__device__ __forceinline__ void load_lds16(const void* g, void* l) {
  __builtin_amdgcn_global_load_lds(
      (const __attribute__((address_space(1))) unsigned int*)g,
      (__attribute__((address_space(3))) unsigned int*)l, 16, 0, 0);
}

__device__ __forceinline__ void barrier_raw() {
  asm volatile("" ::: "memory");
  __builtin_amdgcn_s_barrier();
  asm volatile("" ::: "memory");
}

// ---- spline+rbf feature table: T[k] = 8 x i8 of round(63.5*(b_j+rbf_j)) ----
__global__ __launch_bounds__(256) void tbl_kernel(unsigned char* __restrict__ T) {
  const int k = blockIdx.x * 256 + threadIdx.x;   // grid = TBL_N/256
  const float xn = TBL_X0 + (TBL_W / TBL_N) * k;
  float b[11];
#pragma unroll
  for (int j = 0; j < 11; ++j) {
    const float gj = 0.6f * j - 3.3f;
    b[j] = (xn >= gj && xn < gj + 0.6f) ? 1.f : 0.f;
  }
#pragma unroll
  for (int kk = 1; kk <= 3; ++kk) {
    const float inv = 1.f / (0.6f * kk);
#pragma unroll
    for (int j = 0; j <= 10 - kk; ++j) {
      const float gj = 0.6f * j - 3.3f;
      b[j] = (xn - gj) * inv * b[j] + (gj + 0.6f * (kk + 1) - xn) * inv * b[j + 1];
    }
  }
  float f[8];
#pragma unroll
  for (int j = 0; j < 8; ++j) {
    const float c = -1.5f + (3.f / 7.f) * j;
    const float tt = (xn - c) * (7.f / 3.f);
    f[j] = b[j] + __expf(-tt * tt);
  }
  *reinterpret_cast<uint2*>(T + (size_t)k * 8) =
      make_uint2(pk4(f[0], f[1], f[2], f[3], SCALE_F),
                 pk4(f[4], f[5], f[6], f[7], SCALE_F));
}

// ---------------- base weights -> bf16 [NOUT][KB] ----------------
__global__ __launch_bounds__(256) void wconv_b(
    const float* __restrict__ bw, unsigned short* __restrict__ Wb) {
  const size_t idx = ((size_t)blockIdx.x * 256 + threadIdx.x) * 4;
  float4 f = *reinterpret_cast<const float4*>(bw + idx);
  union { unsigned short us[4]; uint2 u2; } o;
  o.us[0] = f2bf(f.x); o.us[1] = f2bf(f.y); o.us[2] = f2bf(f.z); o.us[3] = f2bf(f.w);
  *reinterpret_cast<uint2*>(Wb + idx) = o.u2;
}

// ------------- spline weights -> i8 x SCALE_W, linear [NOUT][KS] ------------
__global__ __launch_bounds__(256) void wconv_s(
    const float* __restrict__ sw, unsigned char* __restrict__ Ws) {
  const size_t base = ((size_t)blockIdx.x * 256 + threadIdx.x) * 8;
  float4 v0 = *reinterpret_cast<const float4*>(sw + base);
  float4 v1 = *reinterpret_cast<const float4*>(sw + base + 4);
  *reinterpret_cast<uint2*>(Ws + base) =
      make_uint2(pk4(v0.x, v0.y, v0.z, v0.w, SCALE_W),
                 pk4(v1.x, v1.y, v1.z, v1.w, SCALE_W));
}

// -------- LayerNorm + silu(bf16) + table-lookup spline+rbf (i8) -------------
__global__ __launch_bounds__(256) void feat_kernel(
    const float* __restrict__ x, const float* __restrict__ lnw,
    const float* __restrict__ lnb, const unsigned char* __restrict__ T,
    unsigned short* __restrict__ Fb, unsigned char* __restrict__ Fs, int row0) {
  const int row = row0 + blockIdx.x;
  const float* xr = x + (size_t)row * D_IN;
  const int t = threadIdx.x;
  float v[4];
  float s = 0.f, s2 = 0.f;
#pragma unroll
  for (int i = 0; i < 4; ++i) {
    v[i] = xr[t + 256 * i];
    s += v[i];
    s2 += v[i] * v[i];
  }
#pragma unroll
  for (int off = 32; off > 0; off >>= 1) {
    s += __shfl_xor(s, off);
    s2 += __shfl_xor(s2, off);
  }
  __shared__ float red[8];
  const int wid = t >> 6;
  if ((t & 63) == 0) { red[wid] = s; red[4 + wid] = s2; }
  __syncthreads();
  s  = red[0] + red[1] + red[2] + red[3];
  s2 = red[4] + red[5] + red[6] + red[7];
  const float mu = s * (1.f / D_IN);
  const float var = s2 * (1.f / D_IN) - mu * mu;
  const float rstd = rsqrtf(var + 1e-5f);
  unsigned short* fbr = Fb + (size_t)blockIdx.x * KB;
  unsigned char*  fsr = Fs + (size_t)blockIdx.x * KS;
#pragma unroll
  for (int i = 0; i < 4; ++i) {
    const int d = t + 256 * i;
    const float xn = (v[i] - mu) * rstd * lnw[d] + lnb[d];
    const float e = __expf(-xn);
    fbr[d] = f2bf(xn * __builtin_amdgcn_rcpf(1.f + e));   // SiLU
    int ti = (int)rintf((xn - TBL_X0) * (TBL_N / TBL_W));
    ti = min(max(ti, 0), TBL_N - 1);
    *reinterpret_cast<uint2*>(fsr + d * 8) =
        *reinterpret_cast<const uint2*>(T + (size_t)ti * 8);
  }
}

// ---- fused GEMM: C = Fb@Wb^T (bf16) + (Fs@Ws^T)/(SF*SW) (i8), one write ----
// 256x128 tile, 8 waves 4Mx2N, ring-3 LDS shared by both phases (same sizes).
__global__ __launch_bounds__(512, 2) void gemm_fused(
    const unsigned char* __restrict__ Fs, const unsigned char* __restrict__ Ws,
    const unsigned short* __restrict__ Fb, const unsigned short* __restrict__ Wb,
    float* __restrict__ C, int row0) {
  __shared__ __align__(16) char smem[3 * 32768 + 3 * 16384];   // 144 KB
  unsigned char* As8 = (unsigned char*)smem;                   // 3 x 32 KB
  unsigned char* Bs8 = (unsigned char*)(smem + 98304);         // 3 x 16 KB
  const int t = threadIdx.x;
  const int w = t >> 6, l = t & 63;
  const int wr = w >> 1, wc = w & 1;          // 4x2 waves, 64x64 each
  const int id = blockIdx.x;
  const int nbm = gridDim.x >> 3;
  int bm, bn;
  if ((nbm & 7) == 0) {
    const int c = id & 7, j = id >> 3, q = nbm >> 3;
    bm = c + 8 * (j % q);                     // bm%8 == XCD id
    bn = j / q;
  } else { bm = id % nbm; bn = id / nbm; }

  const int hi = l >> 4, l15 = l & 15, rs = l & 7;
  const int arow = l >> 3;             // row within an 8-row staging segment
  const int achk = (l & 7) ^ arow;     // pre-swizzled source chunk

  // ================= phase 1: i8 spline branch, K = 8192 =================
  i32x4 acc[4][4] = {};
  {
    const size_t Ab = (size_t)bm * GM * KS;
    const size_t Bb = (size_t)bn * GN * KS;
    auto stageA = [&](int buf, int k0) {
#pragma unroll
      for (int i = 0; i < 4; ++i) {
        const int ch = i * 512 + t;           // 2048 chunks: row=ch>>3, c=ch&7
        const int r = ch >> 3, c = ch & 7;
        load_lds16(Fs + Ab + (size_t)r * KS + k0 + ((c ^ (r & 7)) * 16),
                   As8 + buf * 32768 + ch * 16);
      }
    };
    auto stageB = [&](int buf, int k0) {
#pragma unroll
      for (int i = 0; i < 2; ++i) {
        const int ch = i * 512 + t;           // 1024 chunks
        const int r = ch >> 3, c = ch & 7;
        load_lds16(Ws + Bb + (size_t)r * KS + k0 + ((c ^ (r & 7)) * 16),
                   Bs8 + buf * 16384 + ch * 16);
      }
    };
    const int c0 = (hi ^ rs) * 16;            // ks=0 swizzled chunk
    const int c1 = ((4 + hi) ^ rs) * 16;      // ks=1
    i32x4 a0[4], a1[4], b0[4], b1[4];
    auto dsread = [&](int buf) {
      const char* Asb = (const char*)(As8 + buf * 32768);
      const char* Bsb = (const char*)(Bs8 + buf * 16384);
#pragma unroll
      for (int m = 0; m < 4; ++m) {
        a0[m] = *reinterpret_cast<const i32x4*>(Asb + (wr * 64 + l15 + m * 16) * 128 + c0);
        a1[m] = *reinterpret_cast<const i32x4*>(Asb + (wr * 64 + l15 + m * 16) * 128 + c1);
      }
#pragma unroll
      for (int n = 0; n < 4; ++n) {
        b0[n] = *reinterpret_cast<const i32x4*>(Bsb + (wc * 64 + l15 + n * 16) * 128 + c0);
        b1[n] = *reinterpret_cast<const i32x4*>(Bsb + (wc * 64 + l15 + n * 16) * 128 + c1);
      }
    };
    auto domfma = [&]() {
      __builtin_amdgcn_s_setprio(1);
#pragma unroll
      for (int m = 0; m < 4; ++m)
#pragma unroll
        for (int n = 0; n < 4; ++n)
          acc[m][n] = __builtin_amdgcn_mfma_i32_16x16x64_i8(a0[m], b0[n], acc[m][n], 0, 0, 0);
#pragma unroll
      for (int m = 0; m < 4; ++m)
#pragma unroll
        for (int n = 0; n < 4; ++n)
          acc[m][n] = __builtin_amdgcn_mfma_i32_16x16x64_i8(a1[m], b1[n], acc[m][n], 0, 0, 0);
      __builtin_amdgcn_s_setprio(0);
    };
    const int NT = KS / GKS;           // 64
    stageA(0, 0); stageB(0, 0);
    stageA(1, GKS); stageB(1, GKS);
    asm volatile("s_waitcnt vmcnt(6)" ::: "memory");
    barrier_raw();
    int cur = 0;
    for (int tt = 0; tt < NT; ++tt) {
      int pre = cur + 2; if (pre >= 3) pre -= 3;
      const bool have2 = (tt + 2 < NT);
      dsread(cur);
      if (have2) { stageA(pre, (tt + 2) * GKS); stageB(pre, (tt + 2) * GKS); }
      __builtin_amdgcn_sched_barrier(0);
      domfma();
      if (tt + 1 < NT) {
        if (have2) asm volatile("s_waitcnt vmcnt(6)" ::: "memory");
        else       asm volatile("s_waitcnt vmcnt(0)" ::: "memory");
        barrier_raw();
      }
      cur = cur + 1; if (cur >= 3) cur = 0;
    }
  }
  barrier_raw();    // all phase-1 LDS reads retired before phase-2 staging

  // ================= phase 2: bf16 base branch, K = 1024 =================
  f32x4 accf[4][4] = {};
  {
    unsigned short* As = (unsigned short*)As8;   // buf stride 16384 elems
    unsigned short* Bs = (unsigned short*)Bs8;   // buf stride 8192 elems
    const size_t Abase = (size_t)bm * GM * KB;
    const size_t Bbase = (size_t)bn * GN * KB;
    auto stageA = [&](int buf, int k0) {
#pragma unroll
      for (int i = 0; i < 4; ++i) {
        const int seg = w * 4 + i;
        load_lds16(Fb + Abase + (size_t)(seg * 8 + arow) * KB + k0 + achk * 8,
                   (char*)(As + buf * 16384) + seg * 1024);
      }
    };
    auto stageB = [&](int buf, int k0) {
#pragma unroll
      for (int i = 0; i < 2; ++i) {
        const int seg = w * 2 + i;
        load_lds16(Wb + Bbase + (size_t)(seg * 8 + arow) * KB + k0 + achk * 8,
                   (char*)(Bs + buf * 8192) + seg * 1024);
      }
    };
    const int rA = wr * 64 + l15;
    const int rB = wc * 64 + l15;
    auto dsread = [&](int buf, int kk, bf16x8* a, bf16x8* b) {
      const int cb = ((kk * 4 + hi) ^ rs) * 16;
#pragma unroll
      for (int m = 0; m < 4; ++m)
        a[m] = *reinterpret_cast<const bf16x8*>(
            (const char*)(As + buf * 16384) + (rA + m * 16) * 128 + cb);
#pragma unroll
      for (int n = 0; n < 4; ++n)
        b[n] = *reinterpret_cast<const bf16x8*>(
            (const char*)(Bs + buf * 8192) + (rB + n * 16) * 128 + cb);
    };
    auto domfma = [&](bf16x8* a, bf16x8* b) {
      __builtin_amdgcn_s_setprio(1);
#pragma unroll
      for (int m = 0; m < 4; ++m)
#pragma unroll
        for (int n = 0; n < 4; ++n)
          accf[m][n] = __builtin_amdgcn_mfma_f32_16x16x32_bf16(a[m], b[n], accf[m][n], 0, 0, 0);
      __builtin_amdgcn_s_setprio(0);
    };
    const int NT = KB / GK;            // 16
    stageA(0, 0); stageB(0, 0);
    stageA(1, GK); stageB(1, GK);
    asm volatile("s_waitcnt vmcnt(6)" ::: "memory");
    barrier_raw();
    int cur = 0;
    for (int tt = 0; tt < NT; ++tt) {
      int pre = cur + 2; if (pre >= 3) pre -= 3;
      const bool have2 = (tt + 2 < NT);
      bf16x8 a0[4], b0[4], a1[4], b1[4];
      dsread(cur, 0, a0, b0);
      dsread(cur, 1, a1, b1);
      if (have2) { stageA(pre, (tt + 2) * GK); stageB(pre, (tt + 2) * GK); }
      __builtin_amdgcn_sched_barrier(0);
      domfma(a0, b0);
      __builtin_amdgcn_sched_barrier(0);
      domfma(a1, b1);
      if (tt + 1 < NT) {
        if (have2) asm volatile("s_waitcnt vmcnt(6)" ::: "memory");
        else       asm volatile("s_waitcnt vmcnt(0)" ::: "memory");
        barrier_raw();
      }
      cur = cur + 1; if (cur >= 3) cur = 0;
    }
  }

  // ---------------- epilogue: single C write ----------------
  const float sc = 1.0f / (SCALE_F * SCALE_W);
  const int crow0 = row0 + bm * GM + wr * 64 + hi * 4;
  const int ccol0 = bn * GN + wc * 64 + l15;
#pragma unroll
  for (int m = 0; m < 4; ++m)
#pragma unroll
    for (int n = 0; n < 4; ++n) {
      float* cp = C + (size_t)(crow0 + m * 16) * NOUT + ccol0 + n * 16;
#pragma unroll
      for (int r = 0; r < 4; ++r)
        cp[(size_t)r * NOUT] = accf[m][n][r] + (float)acc[m][n][r] * sc;
    }
}

extern "C" void kernel_launch(void* const* d_in, const int* in_sizes, int n_in,
                              void* d_out, int out_size, void* d_ws, size_t ws_size,
                              hipStream_t stream) {
  const float* x   = (const float*)d_in[0];
  const float* lnw = (const float*)d_in[1];
  const float* lnb = (const float*)d_in[2];
  const float* bw  = (const float*)d_in[3];
  const float* sw  = (const float*)d_in[4];
  float* out = (float*)d_out;
  char* ws = (char*)d_ws;

  const size_t tbl_bytes = (size_t)TBL_N * 8;       // 16 KB
  const size_t wb_bytes = (size_t)NOUT * KB * 2;    // 2 MB
  const size_t wsq_bytes = (size_t)NOUT * KS;       // 8 MB
  unsigned char*  T   = (unsigned char*)ws;
  unsigned short* Wb  = (unsigned short*)(ws + tbl_bytes);
  unsigned char*  Wsp = (unsigned char*)(ws + tbl_bytes + wb_bytes);
  char* fbase = ws + tbl_bytes + wb_bytes + wsq_bytes;

  const size_t hdr = tbl_bytes + wb_bytes + wsq_bytes;
  const size_t per_row = (size_t)KB * 2 + KS;       // 10240 B
  size_t avail = (ws_size > hdr) ? ws_size - hdr : 0;
  long long cm = (long long)(avail / per_row);
  cm &= ~255LL;
  if (cm < 256) cm = 256;
  if (cm > B_ROWS) cm = B_ROWS;
  const int chunkM = (int)cm;
  unsigned short* Fb = (unsigned short*)fbase;
  unsigned char*  Fs = (unsigned char*)(fbase + (size_t)chunkM * KB * 2);

  tbl_kernel<<<TBL_N / 256, 256, 0, stream>>>(T);
  wconv_b<<<(NOUT * KB / 4) / 256, 256, 0, stream>>>(bw, Wb);
  wconv_s<<<(NOUT * KS / 8) / 256, 256, 0, stream>>>(sw, Wsp);
  for (int r0 = 0; r0 < B_ROWS; r0 += chunkM) {
    int rows = B_ROWS - r0; if (rows > chunkM) rows = chunkM;
    feat_kernel<<<rows, 256, 0, stream>>>(x, lnw, lnb, T, Fb, Fs, r0);
    gemm_fused<<<dim3((rows / GM) * (NOUT / GN)), 512, 0, stream>>>(
        Fs, Wsp, Fb, Wb, out, r0);
  }
}

// Round 13
// 111.040 us; speedup vs baseline: 2.3422x; 1.0154x over previous
//
#include <hip/hip_runtime.h>

#define B_ROWS 8192
#define D_IN   1024
#define NOUT   1024
#define KB     1024          // base-branch K (bf16)
#define KS     8192          // spline-branch K (i8)
#define GT     128           // block tile (M and N)
#define GK     64            // bf16 K-tile
#define GKS    128           // i8 K-tile (bytes == elements)

#define TBL_N  2048
#define TBL_X0 (-5.5f)
#define TBL_W  11.0f

typedef __attribute__((ext_vector_type(4))) float f32x4;
typedef __attribute__((ext_vector_type(4))) int   i32x4;
typedef __attribute__((ext_vector_type(8))) short bf16x8;

#define SCALE_F 63.5f
#define SCALE_W 11494.728f   // 127 * sqrt(8192)

__device__ __forceinline__ unsigned short f2bf(float f) {
  union { float f; unsigned u; } v; v.f = f;
  unsigned r = v.u + 0x7fffu + ((v.u >> 16) & 1u);   // RNE
  return (unsigned short)(r >> 16);
}

__device__ __forceinline__ unsigned pk4(float a, float b, float c, float d, float s) {
  int qa = (int)rintf(fminf(fmaxf(a * s, -127.f), 127.f));
  int qb = (int)rintf(fminf(fmaxf(b * s, -127.f), 127.f));
  int qc = (int)rintf(fminf(fmaxf(c * s, -127.f), 127.f));
  int qd = (int)rintf(fminf(fmaxf(d * s, -127.f), 127.f));
  return (unsigned)(qa & 255) | ((unsigned)(qb & 255) << 8) |
         ((unsigned)(qc & 255) << 16) | ((unsigned)(qd & 255) << 24);
}

__device__ __forceinline__ void load_lds16(const void* g, void* l) {
  __builtin_amdgcn_global_load_lds(
      (const __attribute__((address_space(1))) unsigned int*)g,
      (__attribute__((address_space(3))) unsigned int*)l, 16, 0, 0);
}

__device__ __forceinline__ void barrier_raw() {
  asm volatile("" ::: "memory");
  __builtin_amdgcn_s_barrier();
  asm volatile("" ::: "memory");
}

// ---- spline+rbf feature table: T[k] = 8 x i8 of round(63.5*(b_j+rbf_j)) ----
__global__ __launch_bounds__(256) void tbl_kernel(unsigned char* __restrict__ T) {
  const int k = blockIdx.x * 256 + threadIdx.x;   // grid = TBL_N/256
  const float xn = TBL_X0 + (TBL_W / TBL_N) * k;
  float b[11];
#pragma unroll
  for (int j = 0; j < 11; ++j) {
    const float gj = 0.6f * j - 3.3f;
    b[j] = (xn >= gj && xn < gj + 0.6f) ? 1.f : 0.f;
  }
#pragma unroll
  for (int kk = 1; kk <= 3; ++kk) {
    const float inv = 1.f / (0.6f * kk);
#pragma unroll
    for (int j = 0; j <= 10 - kk; ++j) {
      const float gj = 0.6f * j - 3.3f;
      b[j] = (xn - gj) * inv * b[j] + (gj + 0.6f * (kk + 1) - xn) * inv * b[j + 1];
    }
  }
  float f[8];
#pragma unroll
  for (int j = 0; j < 8; ++j) {
    const float c = -1.5f + (3.f / 7.f) * j;
    const float tt = (xn - c) * (7.f / 3.f);
    f[j] = b[j] + __expf(-tt * tt);
  }
  *reinterpret_cast<uint2*>(T + (size_t)k * 8) =
      make_uint2(pk4(f[0], f[1], f[2], f[3], SCALE_F),
                 pk4(f[4], f[5], f[6], f[7], SCALE_F));
}

// ---------------- base weights -> bf16 [NOUT][KB] ----------------
__global__ __launch_bounds__(256) void wconv_b(
    const float* __restrict__ bw, unsigned short* __restrict__ Wb) {
  const size_t idx = ((size_t)blockIdx.x * 256 + threadIdx.x) * 4;
  float4 f = *reinterpret_cast<const float4*>(bw + idx);
  union { unsigned short us[4]; uint2 u2; } o;
  o.us[0] = f2bf(f.x); o.us[1] = f2bf(f.y); o.us[2] = f2bf(f.z); o.us[3] = f2bf(f.w);
  *reinterpret_cast<uint2*>(Wb + idx) = o.u2;
}

// ------------- spline weights -> i8 x SCALE_W, linear [NOUT][KS] ------------
__global__ __launch_bounds__(256) void wconv_s(
    const float* __restrict__ sw, unsigned char* __restrict__ Ws) {
  const size_t base = ((size_t)blockIdx.x * 256 + threadIdx.x) * 8;
  float4 v0 = *reinterpret_cast<const float4*>(sw + base);
  float4 v1 = *reinterpret_cast<const float4*>(sw + base + 4);
  *reinterpret_cast<uint2*>(Ws + base) =
      make_uint2(pk4(v0.x, v0.y, v0.z, v0.w, SCALE_W),
                 pk4(v1.x, v1.y, v1.z, v1.w, SCALE_W));
}

// -------- LayerNorm + silu(bf16) + table-lookup spline+rbf (i8) -------------
__global__ __launch_bounds__(256) void feat_kernel(
    const float* __restrict__ x, const float* __restrict__ lnw,
    const float* __restrict__ lnb, const unsigned char* __restrict__ T,
    unsigned short* __restrict__ Fb, unsigned char* __restrict__ Fs, int row0) {
  const int row = row0 + blockIdx.x;
  const float* xr = x + (size_t)row * D_IN;
  const int t = threadIdx.x;
  float v[4];
  float s = 0.f, s2 = 0.f;
#pragma unroll
  for (int i = 0; i < 4; ++i) {
    v[i] = xr[t + 256 * i];
    s += v[i];
    s2 += v[i] * v[i];
  }
#pragma unroll
  for (int off = 32; off > 0; off >>= 1) {
    s += __shfl_xor(s, off);
    s2 += __shfl_xor(s2, off);
  }
  __shared__ float red[8];
  const int wid = t >> 6;
  if ((t & 63) == 0) { red[wid] = s; red[4 + wid] = s2; }
  __syncthreads();
  s  = red[0] + red[1] + red[2] + red[3];
  s2 = red[4] + red[5] + red[6] + red[7];
  const float mu = s * (1.f / D_IN);
  const float var = s2 * (1.f / D_IN) - mu * mu;
  const float rstd = rsqrtf(var + 1e-5f);
  unsigned short* fbr = Fb + (size_t)blockIdx.x * KB;
  unsigned char*  fsr = Fs + (size_t)blockIdx.x * KS;
#pragma unroll
  for (int i = 0; i < 4; ++i) {
    const int d = t + 256 * i;
    const float xn = (v[i] - mu) * rstd * lnw[d] + lnb[d];
    const float e = __expf(-xn);
    fbr[d] = f2bf(xn * __builtin_amdgcn_rcpf(1.f + e));   // SiLU
    int ti = (int)rintf((xn - TBL_X0) * (TBL_N / TBL_W));
    ti = min(max(ti, 0), TBL_N - 1);
    *reinterpret_cast<uint2*>(fsr + d * 8) =
        *reinterpret_cast<const uint2*>(T + (size_t)ti * 8);
  }
}

// ---- fused GEMM: C = Fb@Wb^T (bf16) + (Fs@Ws^T)/(SF*SW) (i8) ----
// 128x128 tile, 4 waves 2x2 (64x64 each), ring-2 dbuf, 64 KB LDS -> 2 blk/CU.
__global__ __launch_bounds__(256, 2) void gemm_fused(
    const unsigned char* __restrict__ Fs, const unsigned char* __restrict__ Ws,
    const unsigned short* __restrict__ Fb, const unsigned short* __restrict__ Wb,
    float* __restrict__ C, int row0) {
  __shared__ __align__(16) char smem[65536];            // 64 KB
  unsigned char* As8 = (unsigned char*)smem;            // 2 x 16 KB
  unsigned char* Bs8 = (unsigned char*)(smem + 32768);  // 2 x 16 KB
  const int t = threadIdx.x;
  const int w = t >> 6, l = t & 63;
  const int wr = w >> 1, wc = w & 1;          // 2x2 waves, 64x64 each
  const int id = blockIdx.x;
  const int nbm = gridDim.x >> 3;             // grid = nbm * 8
  int bm, bn;
  if ((nbm & 7) == 0) {
    const int c = id & 7, j = id >> 3, q = nbm >> 3;
    bm = c + 8 * (j % q);                     // bm%8 == XCD id
    bn = j / q;
  } else { bm = id % nbm; bn = id / nbm; }

  const int hi = l >> 4, l15 = l & 15, rs = l & 7;

  // ================= phase 1: i8 spline branch, K = 8192 =================
  i32x4 acc[4][4] = {};
  {
    const size_t Ab = (size_t)bm * GT * KS;
    const size_t Bb = (size_t)bn * GT * KS;
    // 16 KB tile = 1024 16B-chunks; row=ch>>3 (128 rows x 128 B), c=ch&7
    auto stage = [&](int buf, int k0) {
#pragma unroll
      for (int i = 0; i < 4; ++i) {
        const int ch = i * 256 + t;
        const int r = ch >> 3, c = ch & 7;
        load_lds16(Fs + Ab + (size_t)r * KS + k0 + ((c ^ (r & 7)) * 16),
                   As8 + buf * 16384 + ch * 16);
      }
#pragma unroll
      for (int i = 0; i < 4; ++i) {
        const int ch = i * 256 + t;
        const int r = ch >> 3, c = ch & 7;
        load_lds16(Ws + Bb + (size_t)r * KS + k0 + ((c ^ (r & 7)) * 16),
                   Bs8 + buf * 16384 + ch * 16);
      }
    };
    const int c0 = (hi ^ rs) * 16;            // ks=0 swizzled chunk
    const int c1 = ((4 + hi) ^ rs) * 16;      // ks=1
    i32x4 a0[4], a1[4], b0[4], b1[4];
    auto dsread = [&](int buf) {
      const char* Asb = (const char*)(As8 + buf * 16384);
      const char* Bsb = (const char*)(Bs8 + buf * 16384);
#pragma unroll
      for (int m = 0; m < 4; ++m) {
        a0[m] = *reinterpret_cast<const i32x4*>(Asb + (wr * 64 + l15 + m * 16) * 128 + c0);
        a1[m] = *reinterpret_cast<const i32x4*>(Asb + (wr * 64 + l15 + m * 16) * 128 + c1);
      }
#pragma unroll
      for (int n = 0; n < 4; ++n) {
        b0[n] = *reinterpret_cast<const i32x4*>(Bsb + (wc * 64 + l15 + n * 16) * 128 + c0);
        b1[n] = *reinterpret_cast<const i32x4*>(Bsb + (wc * 64 + l15 + n * 16) * 128 + c1);
      }
    };
    auto domfma = [&]() {
      __builtin_amdgcn_s_setprio(1);
#pragma unroll
      for (int m = 0; m < 4; ++m)
#pragma unroll
        for (int n = 0; n < 4; ++n)
          acc[m][n] = __builtin_amdgcn_mfma_i32_16x16x64_i8(a0[m], b0[n], acc[m][n], 0, 0, 0);
#pragma unroll
      for (int m = 0; m < 4; ++m)
#pragma unroll
        for (int n = 0; n < 4; ++n)
          acc[m][n] = __builtin_amdgcn_mfma_i32_16x16x64_i8(a1[m], b1[n], acc[m][n], 0, 0, 0);
      __builtin_amdgcn_s_setprio(0);
    };
    const int NT = KS / GKS;           // 64
    stage(0, 0);
    int cur = 0;
    for (int tt = 0; tt < NT; ++tt) {
      asm volatile("s_waitcnt vmcnt(0)" ::: "memory");   // tile tt landed
      barrier_raw();                    // publish; prev reads of buf^1 retired
      if (tt + 1 < NT) stage(cur ^ 1, (tt + 1) * GKS);   // loads fly under MFMA
      dsread(cur);
      __builtin_amdgcn_sched_barrier(0);
      domfma();
      cur ^= 1;
    }
  }
  barrier_raw();    // all phase-1 LDS reads retired before phase-2 staging

  // ================= phase 2: bf16 base branch, K = 1024 =================
  f32x4 accf[4][4] = {};
  {
    const size_t Abase = (size_t)bm * GT * KB;
    const size_t Bbase = (size_t)bn * GT * KB;
    // 16 KB tile = 128 rows x 64 bf16 (128 B); same chunk geometry as i8
    auto stage = [&](int buf, int k0) {
#pragma unroll
      for (int i = 0; i < 4; ++i) {
        const int ch = i * 256 + t;
        const int r = ch >> 3, c = ch & 7;
        load_lds16(Fb + Abase + (size_t)r * KB + k0 + ((c ^ (r & 7)) * 8),
                   As8 + buf * 16384 + ch * 16);
      }
#pragma unroll
      for (int i = 0; i < 4; ++i) {
        const int ch = i * 256 + t;
        const int r = ch >> 3, c = ch & 7;
        load_lds16(Wb + Bbase + (size_t)r * KB + k0 + ((c ^ (r & 7)) * 8),
                   Bs8 + buf * 16384 + ch * 16);
      }
    };
    bf16x8 a0[4], b0[4], a1[4], b1[4];
    auto dsread = [&](int buf) {
      const char* Asb = (const char*)(As8 + buf * 16384);
      const char* Bsb = (const char*)(Bs8 + buf * 16384);
      const int cb0 = (hi ^ rs) * 16;
      const int cb1 = ((4 + hi) ^ rs) * 16;
#pragma unroll
      for (int m = 0; m < 4; ++m) {
        a0[m] = *reinterpret_cast<const bf16x8*>(Asb + (wr * 64 + l15 + m * 16) * 128 + cb0);
        a1[m] = *reinterpret_cast<const bf16x8*>(Asb + (wr * 64 + l15 + m * 16) * 128 + cb1);
      }
#pragma unroll
      for (int n = 0; n < 4; ++n) {
        b0[n] = *reinterpret_cast<const bf16x8*>(Bsb + (wc * 64 + l15 + n * 16) * 128 + cb0);
        b1[n] = *reinterpret_cast<const bf16x8*>(Bsb + (wc * 64 + l15 + n * 16) * 128 + cb1);
      }
    };
    auto domfma = [&]() {
      __builtin_amdgcn_s_setprio(1);
#pragma unroll
      for (int m = 0; m < 4; ++m)
#pragma unroll
        for (int n = 0; n < 4; ++n)
          accf[m][n] = __builtin_amdgcn_mfma_f32_16x16x32_bf16(a0[m], b0[n], accf[m][n], 0, 0, 0);
#pragma unroll
      for (int m = 0; m < 4; ++m)
#pragma unroll
        for (int n = 0; n < 4; ++n)
          accf[m][n] = __builtin_amdgcn_mfma_f32_16x16x32_bf16(a1[m], b1[n], accf[m][n], 0, 0, 0);
      __builtin_amdgcn_s_setprio(0);
    };
    const int NT = KB / GK;            // 16
    stage(0, 0);
    int cur = 0;
    for (int tt = 0; tt < NT; ++tt) {
      asm volatile("s_waitcnt vmcnt(0)" ::: "memory");
      barrier_raw();
      if (tt + 1 < NT) stage(cur ^ 1, (tt + 1) * GK);
      dsread(cur);
      __builtin_amdgcn_sched_barrier(0);
      domfma();
      cur ^= 1;
    }
  }

  // ---------------- epilogue: single C write ----------------
  const float sc = 1.0f / (SCALE_F * SCALE_W);
  const int crow0 = row0 + bm * GT + wr * 64 + hi * 4;
  const int ccol0 = bn * GT + wc * 64 + l15;
#pragma unroll
  for (int m = 0; m < 4; ++m)
#pragma unroll
    for (int n = 0; n < 4; ++n) {
      float* cp = C + (size_t)(crow0 + m * 16) * NOUT + ccol0 + n * 16;
#pragma unroll
      for (int r = 0; r < 4; ++r)
        cp[(size_t)r * NOUT] = accf[m][n][r] + (float)acc[m][n][r] * sc;
    }
}

extern "C" void kernel_launch(void* const* d_in, const int* in_sizes, int n_in,
                              void* d_out, int out_size, void* d_ws, size_t ws_size,
                              hipStream_t stream) {
  const float* x   = (const float*)d_in[0];
  const float* lnw = (const float*)d_in[1];
  const float* lnb = (const float*)d_in[2];
  const float* bw  = (const float*)d_in[3];
  const float* sw  = (const float*)d_in[4];
  float* out = (float*)d_out;
  char* ws = (char*)d_ws;

  const size_t tbl_bytes = (size_t)TBL_N * 8;       // 16 KB
  const size_t wb_bytes = (size_t)NOUT * KB * 2;    // 2 MB
  const size_t wsq_bytes = (size_t)NOUT * KS;       // 8 MB
  unsigned char*  T   = (unsigned char*)ws;
  unsigned short* Wb  = (unsigned short*)(ws + tbl_bytes);
  unsigned char*  Wsp = (unsigned char*)(ws + tbl_bytes + wb_bytes);
  char* fbase = ws + tbl_bytes + wb_bytes + wsq_bytes;

  const size_t hdr = tbl_bytes + wb_bytes + wsq_bytes;
  const size_t per_row = (size_t)KB * 2 + KS;       // 10240 B
  size_t avail = (ws_size > hdr) ? ws_size - hdr : 0;
  long long cm = (long long)(avail / per_row);
  cm &= ~255LL;
  if (cm < 256) cm = 256;
  if (cm > B_ROWS) cm = B_ROWS;
  const int chunkM = (int)cm;
  unsigned short* Fb = (unsigned short*)fbase;
  unsigned char*  Fs = (unsigned char*)(fbase + (size_t)chunkM * KB * 2);

  tbl_kernel<<<TBL_N / 256, 256, 0, stream>>>(T);
  wconv_b<<<(NOUT * KB / 4) / 256, 256, 0, stream>>>(bw, Wb);
  wconv_s<<<(NOUT * KS / 8) / 256, 256, 0, stream>>>(sw, Wsp);
  for (int r0 = 0; r0 < B_ROWS; r0 += chunkM) {
    int rows = B_ROWS - r0; if (rows > chunkM) rows = chunkM;
    feat_kernel<<<rows, 256, 0, stream>>>(x, lnw, lnb, T, Fb, Fs, r0);
    gemm_fused<<<dim3((rows / GT) * (NOUT / GT)), 256, 0, stream>>>(
        Fs, Wsp, Fb, Wb, out, r0);
  }
}